// Round 1
// baseline (872.203 us; speedup 1.0000x reference)
//
#include <hip/hip_runtime.h>
#include <hip/hip_bf16.h>

#define B_ 4
#define T_ 256
#define U_ 128
#define ENC_DIM 512
#define DEC_DIM 640
#define JDIM 512
#define VOCAB 1024

typedef __bf16 bf16x8 __attribute__((ext_vector_type(8)));
typedef float f32x4 __attribute__((ext_vector_type(4)));

// ---------------------------------------------------------------------------
// fast tanh: t = exp(2x); tanh = (t-1)/(t+1).  |x| < ~15 here, no overflow.
__device__ __forceinline__ float fast_tanh(float x) {
    float t = __expf(2.0f * x);
    return (t - 1.0f) * __frcp_rn(t + 1.0f);
}

// ---------------------------------------------------------------------------
// Small fp32 projection GEMM: out[M][512] = A[M][K] @ W[K][512] + bias
template <int K, int RPB>
__global__ __launch_bounds__(256) void proj_gemm(const float* __restrict__ A,
                                                 const float* __restrict__ W,
                                                 const float* __restrict__ bias,
                                                 float* __restrict__ out) {
    __shared__ float alds[RPB][64];
    const int r0 = blockIdx.x * RPB;
    const int tid = threadIdx.x;
    float acc[RPB][2] = {};
    for (int k0 = 0; k0 < K; k0 += 64) {
        __syncthreads();
        for (int i = tid; i < RPB * 64; i += 256) {
            int r = i >> 6, c = i & 63;
            alds[r][c] = A[(r0 + r) * K + k0 + c];
        }
        __syncthreads();
        #pragma unroll 8
        for (int e = 0; e < 64; ++e) {
            float w0 = W[(k0 + e) * 512 + tid];
            float w1 = W[(k0 + e) * 512 + tid + 256];
            #pragma unroll
            for (int r = 0; r < RPB; ++r) {
                float x = alds[r][e];
                acc[r][0] = fmaf(x, w0, acc[r][0]);
                acc[r][1] = fmaf(x, w1, acc[r][1]);
            }
        }
    }
    float b0 = bias[tid], b1 = bias[tid + 256];
    #pragma unroll
    for (int r = 0; r < RPB; ++r) {
        out[(r0 + r) * 512 + tid] = acc[r][0] + b0;
        out[(r0 + r) * 512 + tid + 256] = acc[r][1] + b1;
    }
}

// ---------------------------------------------------------------------------
// W_out [512][1024] fp32  ->  Wt [1024][512] bf16 (transpose + cast)
__global__ __launch_bounds__(256) void transpose_cast(const float* __restrict__ W,
                                                      __bf16* __restrict__ Wt) {
    __shared__ float tile[32][33];
    const int bj = blockIdx.x & 15;   // 512/32 = 16 tiles along J
    const int bv = blockIdx.x >> 4;   // 1024/32 = 32 tiles along V
    const int tx = threadIdx.x & 31, ty = threadIdx.x >> 5;  // 32 x 8
    #pragma unroll
    for (int i = 0; i < 4; ++i) {
        tile[ty + i * 8][tx] = W[(bj * 32 + ty + i * 8) * 1024 + bv * 32 + tx];
    }
    __syncthreads();
    #pragma unroll
    for (int i = 0; i < 4; ++i) {
        Wt[(bv * 32 + ty + i * 8) * 512 + bj * 32 + tx] = (__bf16)tile[tx][ty + i * 8];
    }
}

// ---------------------------------------------------------------------------
// joint[m][j] = tanh(enc[bt][j] + dec[b*U_+u][j]) as bf16, m = bt*U_+u
__global__ __launch_bounds__(256) void joint_tanh(const float* __restrict__ enc,
                                                  const float* __restrict__ dec,
                                                  __bf16* __restrict__ J) {
    const long long idx = (long long)blockIdx.x * 256 + threadIdx.x;  // < 8388608
    const int m = (int)(idx >> 6);
    const int j = ((int)idx & 63) << 3;
    const int bt = m >> 7;        // m / U_
    const int u = m & (U_ - 1);
    const int b = bt >> 8;        // bt / T_
    const float* e = enc + bt * 512 + j;
    const float* d = dec + (b * U_ + u) * 512 + j;
    f32x4 e0 = *(const f32x4*)e, e1 = *(const f32x4*)(e + 4);
    f32x4 d0 = *(const f32x4*)d, d1 = *(const f32x4*)(d + 4);
    bf16x8 r;
    #pragma unroll
    for (int i = 0; i < 4; ++i) {
        r[i]     = (__bf16)fast_tanh(e0[i] + d0[i]);
        r[i + 4] = (__bf16)fast_tanh(e1[i] + d1[i]);
    }
    *(bf16x8*)(J + (long long)m * 512 + j) = r;
}

// ---------------------------------------------------------------------------
// Main GEMM: out[131072][1024] = joint[131072][512](bf16) @ Wt^T + b_out
// 128x128 tile, BK=64, 4 waves (2x2), 4x4 16x16 fragments per wave.
__global__ __launch_bounds__(256) void joint_gemm(const __bf16* __restrict__ Aj,
                                                  const __bf16* __restrict__ Wt,
                                                  const float* __restrict__ bias,
                                                  float* __restrict__ out) {
    __shared__ __bf16 Alds[128 * 64];
    __shared__ __bf16 Blds[128 * 64];
    const int tid = threadIdx.x;
    const int wave = tid >> 6;
    const int lane = tid & 63;
    const int m0 = blockIdx.y << 7;
    const int n0 = blockIdx.x << 7;
    const int wr = wave >> 1, wc = wave & 1;
    const int frow = lane & 15;
    const int kgrp = lane >> 4;

    f32x4 acc[4][4] = {};

    for (int kt = 0; kt < 8; ++kt) {
        __syncthreads();
        // stage A-tile [128 rows][128 B] and B-tile via global_load_lds (16B/lane)
        #pragma unroll
        for (int i = 0; i < 4; ++i) {
            const int offb = wave * 1024 + i * 4096;         // wave-uniform LDS byte base
            const int off = offb + lane * 16;                // per-lane byte in tile
            const int row = off >> 7;
            const int colb = off & 127;
            const char* ga = (const char*)Aj + ((long long)(m0 + row) << 10) + (kt << 7) + colb;
            const char* gb = (const char*)Wt + ((long long)(n0 + row) << 10) + (kt << 7) + colb;
            __builtin_amdgcn_global_load_lds(
                (const __attribute__((address_space(1))) void*)ga,
                (__attribute__((address_space(3))) void*)((char*)Alds + offb), 16, 0, 0);
            __builtin_amdgcn_global_load_lds(
                (const __attribute__((address_space(1))) void*)gb,
                (__attribute__((address_space(3))) void*)((char*)Blds + offb), 16, 0, 0);
        }
        asm volatile("s_waitcnt vmcnt(0)" ::: "memory");
        __syncthreads();

        #pragma unroll
        for (int kk = 0; kk < 2; ++kk) {
            const int kbase = kk * 32 + kgrp * 8;
            bf16x8 af[4], bfr[4];
            #pragma unroll
            for (int m = 0; m < 4; ++m)
                af[m] = *(const bf16x8*)&Alds[(wr * 64 + m * 16 + frow) * 64 + kbase];
            #pragma unroll
            for (int n = 0; n < 4; ++n)
                bfr[n] = *(const bf16x8*)&Blds[(wc * 64 + n * 16 + frow) * 64 + kbase];
            #pragma unroll
            for (int m = 0; m < 4; ++m)
                #pragma unroll
                for (int n = 0; n < 4; ++n)
                    acc[m][n] = __builtin_amdgcn_mfma_f32_16x16x32_bf16(af[m], bfr[n], acc[m][n], 0, 0, 0);
        }
    }

    // epilogue: + bias, fp32 store
    #pragma unroll
    for (int n = 0; n < 4; ++n) {
        const int col = n0 + wc * 64 + n * 16 + frow;
        const float bo = bias[col];
        #pragma unroll
        for (int m = 0; m < 4; ++m) {
            const int row = m0 + wr * 64 + m * 16 + kgrp * 4;
            #pragma unroll
            for (int j = 0; j < 4; ++j)
                out[(long long)(row + j) * 1024 + col] = acc[m][n][j] + bo;
        }
    }
}

// ---------------------------------------------------------------------------
extern "C" void kernel_launch(void* const* d_in, const int* in_sizes, int n_in,
                              void* d_out, int out_size, void* d_ws, size_t ws_size,
                              hipStream_t stream) {
    const float* encoder_out = (const float*)d_in[0];  // [4][256][512]
    const float* decoder_out = (const float*)d_in[1];  // [4][128][640]
    const float* W_enc = (const float*)d_in[2];        // [512][512]
    const float* b_enc = (const float*)d_in[3];        // [512]
    const float* W_dec = (const float*)d_in[4];        // [640][512]
    const float* b_dec = (const float*)d_in[5];        // [512]
    const float* W_out = (const float*)d_in[6];        // [512][1024]
    const float* b_out = (const float*)d_in[7];        // [1024]
    float* out = (float*)d_out;                        // [131072][1024]

    char* ws = (char*)d_ws;
    float* enc_proj = (float*)(ws);                    // 2 MiB  [1024][512]
    float* dec_proj = (float*)(ws + (2 << 20));        // 1 MiB  [512][512]
    __bf16* Wt      = (__bf16*)(ws + (3 << 20));       // 1 MiB  [1024][512]
    __bf16* joint   = (__bf16*)(ws + (4 << 20));       // 128 MiB [131072][512]

    // 1. projections (fp32)
    proj_gemm<ENC_DIM, 4><<<dim3((B_ * T_) / 4), 256, 0, stream>>>(encoder_out, W_enc, b_enc, enc_proj);
    proj_gemm<DEC_DIM, 4><<<dim3((B_ * U_) / 4), 256, 0, stream>>>(decoder_out, W_dec, b_dec, dec_proj);

    // 2. W_out -> bf16 transposed
    transpose_cast<<<dim3(16 * 32), 256, 0, stream>>>(W_out, Wt);

    // 3. joint = tanh(enc + dec) in bf16
    joint_tanh<<<dim3(32768), 256, 0, stream>>>(enc_proj, dec_proj, joint);

    // 4. logits = joint @ W_out + b_out   (bf16 MFMA, fp32 accum)
    joint_gemm<<<dim3(VOCAB / 128, (B_ * T_ * U_) / 128), 256, 0, stream>>>(joint, Wt, b_out, out);
}